// Round 12
// baseline (898.914 us; speedup 1.0000x reference)
//
#include <hip/hip_runtime.h>
#include <cstdint>

// ---------------- types / helpers ----------------
using bf16 = __bf16;
typedef __bf16 bf16x8 __attribute__((ext_vector_type(8)));
typedef float  f32x4  __attribute__((ext_vector_type(4)));

__device__ inline f32x4 mfma16(bf16x8 a, bf16x8 b, f32x4 c) {
  return __builtin_amdgcn_mfma_f32_16x16x32_bf16(a, b, c, 0, 0, 0);
}
__device__ inline float b2f(unsigned short h) {
  unsigned u = ((unsigned)h) << 16;
  return __builtin_bit_cast(float, u);
}
__device__ inline unsigned pack2(float x, float y) {
  return (unsigned)__builtin_bit_cast(unsigned short, (bf16)x)
       | ((unsigned)__builtin_bit_cast(unsigned short, (bf16)y) << 16);
}
__device__ inline void gload16(const void* g, void* l) {
  __builtin_amdgcn_global_load_lds(
      (const __attribute__((address_space(1))) void*)g,
      (__attribute__((address_space(3))) void*)l, 16, 0, 0);
}

#define BATCH 32
#define LTOK  2048
#define HWTOK 1024
#define CDIM  512
#define SM_SCALE 0.044194173824159216f   // 512^-0.5

// ---------------- 256x256 double-buffered GEMM (T3-minimum, m230-V0) ------
// out[M][N] = A[M][K] @ B[N][K]^T -> bf16. BM=BN=256, BK=64, 512 thr
// (8 waves 2M x 4N, each 128x64 output). LDS 128 KiB (2 dbuf x (A+B)) ->
// 1 block/CU, 8 waves. Single barrier per K-tile; prefetch issued BEFORE
// compute so ~64 MFMA/wave x 2 waves/SIMD hide the load latency (the
// catalog's validated minimum-2-phase: STAGE(next) -> COMPUTE(cur) ->
// syncthreads [drains vmcnt(0)]).  XOR swizzle identical to the proven
// 128^2 kernel (row&7 == rA&7 holds; conflicts=0 measured there).
// Register audit: acc 128 + frags 24 + addr ~40 ~= 195 < cap 256 (LB 512,2).
// SMODE: 0 bias (BIAS 1=col 2=row), 1 exp(scale*acc) epilogue. (No SMODE2
// here: rowsum regs would push ~250 -- PV stays on the 128^2 kernel.)
template<int BIAS, bool CONCAT, int SMODE>
__global__ __launch_bounds__(512, 2) void gemm256(
    const bf16* __restrict__ A, const bf16* __restrict__ A2,
    const bf16* __restrict__ Bm, const float* __restrict__ bias,
    bf16* __restrict__ out,
    int N, int K, long bA, long bB, long bO, int nx, int ny)
{
  // ---- bijective XCD chunk remap (m204) ----
  int nwg = gridDim.x, orig = blockIdx.x;
  int q = nwg >> 3, r = nwg & 7;
  int xcd = orig & 7, idx = orig >> 3;
  int wgid = (xcd < r ? xcd * (q + 1) : r * (q + 1) + (xcd - r) * q) + idx;
  int n0 = (wgid % nx) * 256;
  int t2 = wgid / nx;
  int m0 = (t2 % ny) * 256;
  int bz = t2 / ny;

  int tid = threadIdx.x, lane = tid & 63;
  int wid = tid >> 6, lr = lane & 15, lg = lane >> 4;
  int wm = (wid >> 2) * 128, wn = (wid & 3) * 64;   // 2M x 4N waves
  __shared__ __align__(16) bf16 lA[2][256 * 64];    // 2 x 32 KiB
  __shared__ __align__(16) bf16 lB[2][256 * 64];    // 2 x 32 KiB
  const bf16* Ab = A + (long)bz * bA;
  const bf16* Bb = Bm + (long)bz * bB;
  f32x4 acc[8][4] = {};

  int rA  = tid >> 3;               // 0..63; row = c*64 + rA
  int k8  = tid & 7;
  int k8s = k8 ^ (rA & 7);          // source pre-swizzle
  int sx  = (lr & 7) << 3;          // read-side elem XOR

  auto STAGE = [&](int b, int k0) {
    #pragma unroll
    for (int c = 0; c < 4; c++) {
      int row = c * 64 + rA;
      const bf16* g;
      if constexpr (CONCAT) {
        int kg = k0 + k8s * 8;
        g = (kg < 512) ? (A  + ((long)(m0 + row) << 9) + kg)
                       : (A2 + ((long)(m0 + row) << 9) + (kg - 512));
      } else {
        g = Ab + (long)(m0 + row) * K + k0 + k8s * 8;
      }
      gload16(g, (char*)lA[b] + (c * 512 + tid) * 16);
    }
    #pragma unroll
    for (int c = 0; c < 4; c++) {
      int row = c * 64 + rA;
      gload16(Bb + (long)(n0 + row) * K + k0 + k8s * 8,
              (char*)lB[b] + (c * 512 + tid) * 16);
    }
  };
  auto COMPUTE = [&](int b) {
    #pragma unroll
    for (int ss = 0; ss < 2; ss++) {
      int co = (ss * 32 + lg * 8) ^ sx;
      bf16x8 af[8], bg[4];
      #pragma unroll
      for (int t = 0; t < 8; t++)
        af[t] = *(const bf16x8*)&lA[b][(wm + t * 16 + lr) * 64 + co];
      #pragma unroll
      for (int t = 0; t < 4; t++)
        bg[t] = *(const bf16x8*)&lB[b][(wn + t * 16 + lr) * 64 + co];
      #pragma unroll
      for (int fm = 0; fm < 8; fm++)
        #pragma unroll
        for (int fn = 0; fn < 4; fn++)
          acc[fm][fn] = mfma16(af[fm], bg[fn], acc[fm][fn]);
    }
  };

  STAGE(0, 0);
  __syncthreads();                  // drains vmcnt(0): tile 0 resident
  int cur = 0;
  for (int k0 = 64; k0 < K; k0 += 64) {
    STAGE(cur ^ 1, k0);             // prefetch next tile (other buffer)
    COMPUTE(cur);                   // 64 MFMA/wave hide the prefetch
    __syncthreads();                // vmcnt(0): prefetch landed; reads done
    cur ^= 1;
  }
  COMPUTE(cur);

  long obase = (long)bz * bO;
  #pragma unroll
  for (int fm = 0; fm < 8; fm++) {
    #pragma unroll
    for (int i = 0; i < 4; i++) {
      int row = m0 + wm + fm * 16 + lg * 4 + i;
      long rb = obase + (long)row * N;
      #pragma unroll
      for (int fn = 0; fn < 4; fn++) {
        int col = n0 + wn + fn * 16 + lr;
        if constexpr (SMODE == 1) {
          out[rb + col] = (bf16)__expf(acc[fm][fn][i] * SM_SCALE);
        } else {
          float v = acc[fm][fn][i];
          if constexpr (BIAS == 1) v += bias[col];
          if constexpr (BIAS == 2) v += bias[row];
          out[rb + col] = (bf16)v;
        }
      }
    }
  }
}

// ---------------- 128x128 proven core (kept for PV / SMODE2) --------------
template<int BIAS, bool CONCAT, int SMODE>
__global__ __launch_bounds__(256, 4) void gemm_bt(
    const bf16* __restrict__ A, const bf16* __restrict__ A2,
    const bf16* __restrict__ Bm, const float* __restrict__ bias,
    const bf16* __restrict__ resid, bf16* __restrict__ out,
    int N, int K, long bA, long bB, long bO, int nx, int ny)
{
  int nwg = gridDim.x, orig = blockIdx.x;
  int q = nwg >> 3, r = nwg & 7;
  int xcd = orig & 7, idx = orig >> 3;
  int wgid = (xcd < r ? xcd * (q + 1) : r * (q + 1) + (xcd - r) * q) + idx;
  int n0 = (wgid % nx) * 128;
  int t2 = wgid / nx;
  int m0 = (t2 % ny) * 128;
  int bz = t2 / ny;

  int tid = threadIdx.x, lane = tid & 63;
  int wid = tid >> 6, lr = lane & 15, lg = lane >> 4;
  int wm = (wid >> 1) * 64, wn = (wid & 1) * 64;
  __shared__ __align__(16) bf16 lA[128 * 64];
  __shared__ __align__(16) bf16 lB[128 * 64];
  const bf16* Ab = A + (long)bz * bA;
  const bf16* Bb = Bm + (long)bz * bB;
  f32x4 acc[4][4] = {};
  f32x4 rs[4] = {};
  bf16x8 onesf;
  #pragma unroll
  for (int j = 0; j < 8; j++) onesf[j] = (bf16)1.0f;

  int rA  = tid >> 3;
  int k8  = tid & 7;
  int k8s = k8 ^ (rA & 7);
  int sx  = (lr & 7) << 3;

  for (int k0 = 0; k0 < K; k0 += 64) {
    #pragma unroll
    for (int c = 0; c < 4; c++) {
      int row = c * 32 + rA;
      const bf16* g;
      if constexpr (CONCAT) {
        int kg = k0 + k8s * 8;
        g = (kg < 512) ? (A  + ((long)(m0 + row) << 9) + kg)
                       : (A2 + ((long)(m0 + row) << 9) + (kg - 512));
      } else {
        g = Ab + (long)(m0 + row) * K + k0 + k8s * 8;
      }
      gload16(g, (char*)lA + (c * 256 + tid) * 16);
    }
    #pragma unroll
    for (int c = 0; c < 4; c++) {
      int row = c * 32 + rA;
      gload16(Bb + (long)(n0 + row) * K + k0 + k8s * 8,
              (char*)lB + (c * 256 + tid) * 16);
    }
    __syncthreads();
    #pragma unroll
    for (int ss = 0; ss < 2; ss++) {
      int co = (ss * 32 + lg * 8) ^ sx;
      bf16x8 af[4], bg[4];
      #pragma unroll
      for (int t = 0; t < 4; t++)
        af[t] = *(const bf16x8*)&lA[(wm + t * 16 + lr) * 64 + co];
      #pragma unroll
      for (int t = 0; t < 4; t++)
        bg[t] = *(const bf16x8*)&lB[(wn + t * 16 + lr) * 64 + co];
      #pragma unroll
      for (int fm = 0; fm < 4; fm++)
        #pragma unroll
        for (int fn = 0; fn < 4; fn++)
          acc[fm][fn] = mfma16(af[fm], bg[fn], acc[fm][fn]);
      if constexpr (SMODE == 2) {
        #pragma unroll
        for (int fm = 0; fm < 4; fm++)
          rs[fm] = mfma16(af[fm], onesf, rs[fm]);
      }
    }
    __syncthreads();
  }

  long obase = (long)bz * bO;
  #pragma unroll
  for (int fm = 0; fm < 4; fm++) {
    #pragma unroll
    for (int i = 0; i < 4; i++) {
      int row = m0 + wm + fm * 16 + lg * 4 + i;
      long rb = obase + (long)row * N;
      float inv;
      if constexpr (SMODE == 2) inv = 1.0f / rs[fm][i];
      #pragma unroll
      for (int fn = 0; fn < 4; fn++) {
        int col = n0 + wn + fn * 16 + lr;
        if constexpr (SMODE == 1) {
          out[rb + col] = (bf16)__expf(acc[fm][fn][i] * SM_SCALE);
        } else if constexpr (SMODE == 2) {
          float v = acc[fm][fn][i] * inv + (float)resid[rb + col];
          out[rb + col] = (bf16)v;
        } else {
          float v = acc[fm][fn][i];
          if constexpr (BIAS == 1) v += bias[col];
          if constexpr (BIAS == 2) v += bias[row];
          out[rb + col] = (bf16)v;
        }
      }
    }
  }
}

// ---------------- elementwise f32 -> bf16 ---------------------------------
__global__ __launch_bounds__(256) void cvt_k(const float* __restrict__ in,
                                             bf16* __restrict__ out)
{
  long i = ((long)blockIdx.x * 256 + threadIdx.x) * 8;
  float4 a = *(const float4*)(in + i);
  float4 c = *(const float4*)(in + i + 4);
  unsigned o[4];
  o[0] = pack2(a.x, a.y); o[1] = pack2(a.z, a.w);
  o[2] = pack2(c.x, c.y); o[3] = pack2(c.z, c.w);
  *(uint4*)(out + i) = *(uint4*)o;
}

// ---------------- transpose + convert: in[rows][cols] f32 -> out[cols][rows] bf16
__global__ __launch_bounds__(256) void cvtT_k(const float* __restrict__ in,
                                              bf16* __restrict__ out,
                                              int rows, int cols, long bElems)
{
  int bz = blockIdx.z;
  int c0 = blockIdx.x * 64, r0 = blockIdx.y * 64;
  const float* I = in + (long)bz * bElems;
  bf16* O = out + (long)bz * bElems;
  __shared__ __align__(16) bf16 t[64][72];
  int tid = threadIdx.x;
  #pragma unroll
  for (int j = 0; j < 4; j++) {
    int kk = j * 16 + (tid >> 4);
    int mm = (tid & 15) * 4;
    float4 v = *(const float4*)(I + (long)(r0 + kk) * cols + c0 + mm);
    t[mm + 0][kk] = (bf16)v.x; t[mm + 1][kk] = (bf16)v.y;
    t[mm + 2][kk] = (bf16)v.z; t[mm + 3][kk] = (bf16)v.w;
  }
  __syncthreads();
  #pragma unroll
  for (int p = 0; p < 2; p++) {
    int r = (tid >> 3) + p * 32;
    int c8 = tid & 7;
    *(uint4*)(O + (long)(c0 + r) * rows + r0 + c8 * 8) = *(const uint4*)&t[r][c8 * 8];
  }
}

// ---------------- 5 weight transposes (512x512) in one dispatch -----------
__global__ __launch_bounds__(256) void cvtT5_k(const float* __restrict__ p0,
                                               const float* __restrict__ p1,
                                               const float* __restrict__ p2,
                                               const float* __restrict__ p3,
                                               const float* __restrict__ p4,
                                               bf16* __restrict__ out)
{
  int z = blockIdx.z;
  const float* I = z == 0 ? p0 : z == 1 ? p1 : z == 2 ? p2 : z == 3 ? p3 : p4;
  bf16* O = out + (long)z * 262144;
  int c0 = blockIdx.x * 64, r0 = blockIdx.y * 64;
  __shared__ __align__(16) bf16 t[64][72];
  int tid = threadIdx.x;
  #pragma unroll
  for (int j = 0; j < 4; j++) {
    int kk = j * 16 + (tid >> 4);
    int mm = (tid & 15) * 4;
    float4 v = *(const float4*)(I + (long)(r0 + kk) * 512 + c0 + mm);
    t[mm + 0][kk] = (bf16)v.x; t[mm + 1][kk] = (bf16)v.y;
    t[mm + 2][kk] = (bf16)v.z; t[mm + 3][kk] = (bf16)v.w;
  }
  __syncthreads();
  #pragma unroll
  for (int p = 0; p < 2; p++) {
    int r = (tid >> 3) + p * 32;
    int c8 = tid & 7;
    *(uint4*)(O + (long)(c0 + r) * 512 + r0 + c8 * 8) = *(const uint4*)&t[r][c8 * 8];
  }
}

// ---------------- row LayerNorm over 512 bf16, in place -------------------
__global__ __launch_bounds__(256) void ln_k(bf16* __restrict__ T,
                                            const float* __restrict__ g,
                                            const float* __restrict__ b)
{
  int r = blockIdx.x * 4 + (threadIdx.x >> 6);
  int lane = threadIdx.x & 63;
  bf16* row = T + (long)r * 512 + lane * 8;
  uint4 u = *(const uint4*)row;
  float v[8];
  {
    unsigned* up = (unsigned*)&u;
    #pragma unroll
    for (int e = 0; e < 4; e++) { v[2*e] = b2f(up[e] & 0xffff); v[2*e+1] = b2f(up[e] >> 16); }
  }
  float s = 0.f, s2 = 0.f;
  #pragma unroll
  for (int j = 0; j < 8; j++) { s += v[j]; s2 += v[j] * v[j]; }
  #pragma unroll
  for (int k = 1; k < 64; k <<= 1) { s += __shfl_xor(s, k); s2 += __shfl_xor(s2, k); }
  float mu = s * (1.0f / 512.0f);
  float var = s2 * (1.0f / 512.0f) - mu * mu;
  float rsq = rsqrtf(var + 1e-5f);
  float4 g0 = *(const float4*)(g + lane * 8);
  float4 g1 = *(const float4*)(g + lane * 8 + 4);
  float4 b0 = *(const float4*)(b + lane * 8);
  float4 b1 = *(const float4*)(b + lane * 8 + 4);
  float gg[8] = {g0.x,g0.y,g0.z,g0.w,g1.x,g1.y,g1.z,g1.w};
  float bb[8] = {b0.x,b0.y,b0.z,b0.w,b1.x,b1.y,b1.z,b1.w};
  unsigned o[4];
  #pragma unroll
  for (int e = 0; e < 4; e++)
    o[e] = pack2((v[2*e]   - mu) * rsq * gg[2*e]   + bb[2*e],
                 (v[2*e+1] - mu) * rsq * gg[2*e+1] + bb[2*e+1]);
  *(uint4*)row = *(uint4*)o;
}

// ---------------- BatchNorm stats / finalize / apply ----------------------
__global__ __launch_bounds__(256) void bn_stats_k(const bf16* __restrict__ Y,
                                                  float* __restrict__ sums)
{
  long r0 = (long)blockIdx.x * 256; int t = threadIdx.x;
  float s0 = 0, s1 = 0, q0 = 0, q1 = 0;
  for (int j = 0; j < 256; j++) {
    unsigned u = *(const unsigned*)(Y + (r0 + j) * 512 + t * 2);
    float a = b2f((unsigned short)(u & 0xffff));
    float c = b2f((unsigned short)(u >> 16));
    s0 += a; q0 += a * a; s1 += c; q1 += c * c;
  }
  atomicAdd(&sums[t * 2],           s0);
  atomicAdd(&sums[t * 2 + 1],       s1);
  atomicAdd(&sums[512 + t * 2],     q0);
  atomicAdd(&sums[512 + t * 2 + 1], q1);
}

__global__ void bn_finalize_k(const float* __restrict__ sums,
                              const float* __restrict__ bn_g,
                              const float* __restrict__ bn_b,
                              float* __restrict__ ss)
{
  int c = threadIdx.x;   // 512
  const float invN = 1.0f / 65536.0f;
  float mean = sums[c] * invN;
  float var  = sums[512 + c] * invN - mean * mean;
  float sc = bn_g[c] * rsqrtf(var + 1e-5f);
  ss[c] = sc;
  ss[512 + c] = bn_b[c] - mean * sc;
}

__global__ __launch_bounds__(256) void bn_apply_k(const bf16* __restrict__ Y,
                                                  const float* __restrict__ ss,
                                                  float* __restrict__ out)
{
  long idx = ((long)blockIdx.x * 256 + threadIdx.x) * 8;
  int c0 = (int)(idx & 511);
  uint4 u = *(const uint4*)(Y + idx);
  const unsigned* up = (const unsigned*)&u;
  float4 sa = *(const float4*)(ss + c0);
  float4 sb = *(const float4*)(ss + c0 + 4);
  float4 ha = *(const float4*)(ss + 512 + c0);
  float4 hb = *(const float4*)(ss + 512 + c0 + 4);
  float f[8];
  #pragma unroll
  for (int e = 0; e < 4; e++) {
    f[2 * e]     = b2f((unsigned short)(up[e] & 0xffff));
    f[2 * e + 1] = b2f((unsigned short)(up[e] >> 16));
  }
  float4 o0, o1;
  o0.x = fmaxf(0.f, f[0] * sa.x + ha.x);
  o0.y = fmaxf(0.f, f[1] * sa.y + ha.y);
  o0.z = fmaxf(0.f, f[2] * sa.z + ha.z);
  o0.w = fmaxf(0.f, f[3] * sa.w + ha.w);
  o1.x = fmaxf(0.f, f[4] * sb.x + hb.x);
  o1.y = fmaxf(0.f, f[5] * sb.y + hb.y);
  o1.z = fmaxf(0.f, f[6] * sb.z + hb.z);
  o1.w = fmaxf(0.f, f[7] * sb.w + hb.w);
  *(float4*)(out + idx) = o0;
  *(float4*)(out + idx + 4) = o1;
}

// ---------------- launch ---------------------------------------------------
extern "C" void kernel_launch(void* const* d_in, const int* in_sizes, int n_in,
                              void* d_out, int out_size, void* d_ws, size_t ws_size,
                              hipStream_t stream)
{
  (void)in_sizes; (void)n_in; (void)out_size; (void)ws_size;
  const float* Fj  = (const float*)d_in[0];
  const float* Fs  = (const float*)d_in[1];
  const float* Fe  = (const float*)d_in[2];
  const float* Wq  = (const float*)d_in[3];
  const float* bq  = (const float*)d_in[4];
  const float* Wsk = (const float*)d_in[5];
  const float* bsk = (const float*)d_in[6];
  const float* Wsv = (const float*)d_in[7];
  const float* bsv = (const float*)d_in[8];
  const float* Wek = (const float*)d_in[9];
  const float* bek = (const float*)d_in[10];
  const float* Wev = (const float*)d_in[11];
  const float* bev = (const float*)d_in[12];
  const float* lng = (const float*)d_in[13];
  const float* lnb = (const float*)d_in[14];
  const float* Wf  = (const float*)d_in[15];
  const float* bfp = (const float*)d_in[16];
  const float* bng = (const float*)d_in[17];
  const float* bnb = (const float*)d_in[18];

  char* ws = (char*)d_ws;
  // ws map: FjB/T2 0-64MiB | Qb/Yb 64-128 | Kb 128-160 | Vt 160-192 |
  //         weights 192-195.5 | stats. Peak ~196 MiB.
  // d_out (128 MiB): T1 bf16 lower half; upper half = FT then P' (strictly
  // sequential on stream: FT consumed by K/Vt before S overwrites).
  bf16* FjB = (bf16*)(ws);
  bf16* T2  = FjB;                              // attn-1 PV aliases (same-elem)
  bf16* Qb  = (bf16*)(ws + 67108864L);
  bf16* Yb  = Qb;
  bf16* Kb  = (bf16*)(ws + 134217728L);         // 32 MiB K full
  bf16* Vt  = (bf16*)(ws + 167772160L);         // 32 MiB Vt full
  bf16* Wt5 = (bf16*)(ws + 201326592L);         // 5 x 512 KiB weights^T
  bf16* WfB = (bf16*)(ws + 203948032L);         // 1 MiB
  float* stats = (float*)(ws + 204996608L);
  float* ssbuf = (float*)(ws + 205000704L);
  bf16* T1  = (bf16*)d_out;
  bf16* FT  = (bf16*)((char*)d_out + 67108864L);
  bf16* Rg  = FT;                               // P' (64 MiB, 16 batches)
  float* outp = (float*)d_out;

  const long PB_Q  = (long)LTOK * CDIM;      // 1048576
  const long PB_KV = (long)HWTOK * CDIM;     // 524288
  const long PB_S  = (long)LTOK * HWTOK;     // 2097152

  dim3 blk(256), gblk(512);

  // --- conversions (weights + Fj) ---
  cvt_k<<<dim3(16384), blk, 0, stream>>>(Fj, FjB);
  cvt_k<<<dim3(256),   blk, 0, stream>>>(Wf, WfB);
  cvtT5_k<<<dim3(8, 8, 5), blk, 0, stream>>>(Wq, Wsk, Wsv, Wek, Wev, Wt5);

  // --- Q projection: M=65536 N=512 K=512 (256^2 dbuf kernel) ---
  gemm256<1,false,0><<<dim3(512), gblk, 0, stream>>>(
      FjB, nullptr, Wt5, bq, Qb, 512, 512, 0, 0, 0, 2, 256);

  for (int attn = 0; attn < 2; attn++) {
    const float* Fsrc = attn ? Fe : Fs;
    const bf16* WkT = Wt5 + (attn ? 786432 : 262144);
    const bf16* WvT = Wt5 + (attn ? 1048576 : 524288);
    const float* bk = attn ? bek : bsk;
    const float* bv = attn ? bev : bsv;
    bf16* Tout = attn ? T2 : T1;

    // FT[b][m][c] (bf16, d_out upper half) = transpose of Fsrc [b][c][m]
    cvtT_k<<<dim3(16, 8, 32), blk, 0, stream>>>(Fsrc, FT, 512, 1024, PB_KV);

    // K full: per-batch M=1024 N=512 K=512
    gemm256<1,false,0><<<dim3(256), gblk, 0, stream>>>(
        FT, nullptr, WkT, bk, Kb, 512, 512, PB_KV, 0, PB_KV, 2, 4);
    // Vt full: per-batch M=512 N=1024 K=512 (A = WvT, B = FT, row bias)
    gemm256<2,false,0><<<dim3(256), gblk, 0, stream>>>(
        WvT, nullptr, FT, bv, Vt, 1024, 512, 0, PB_KV, PB_KV, 4, 2);

    for (int c = 0; c < 2; c++) {          // 16-batch chunks
      int b0 = c * 16;
      // P' = exp(scale * Q K^T): per-batch M=2048 N=1024 K=512
      gemm256<0,false,1><<<dim3(512), gblk, 0, stream>>>(
          Qb + (long)b0 * PB_Q, nullptr, Kb + (long)b0 * PB_KV,
          nullptr, Rg, 1024, 512, PB_Q, PB_KV, PB_S, 4, 8);
      // T = P'V / rowsum + Fj: per-batch M=2048 N=512 K=1024 (128^2 proven)
      gemm_bt<0,false,2><<<dim3(1024), blk, 0, stream>>>(
          Rg, nullptr, Vt + (long)b0 * PB_KV, nullptr,
          FjB + (long)b0 * PB_Q, Tout + (long)b0 * PB_Q,
          512, 1024, PB_S, PB_KV, PB_Q, 4, 16);
    }
    ln_k<<<dim3(16384), blk, 0, stream>>>(Tout, lng, lnb);
  }

  // --- fusion conv1d: Y = [T1|T2] @ Wf^T + bf (M=65536 N=512 K=1024) ---
  gemm256<1,true,0><<<dim3(512), gblk, 0, stream>>>(
      T1, T2, WfB, bfp, Yb, 512, 1024, 0, 0, 0, 2, 256);

  // --- BatchNorm (train stats) + ReLU -> f32 out ---
  (void)hipMemsetAsync(stats, 0, 4096, stream);
  bn_stats_k<<<dim3(256), blk, 0, stream>>>(Yb, stats);
  bn_finalize_k<<<dim3(1), dim3(512), 0, stream>>>(stats, bng, bnb, ssbuf);
  bn_apply_k<<<dim3(16384), blk, 0, stream>>>(Yb, ssbuf, outp);
}

// Round 13
// 854.712 us; speedup vs baseline: 1.0517x; 1.0517x over previous
//
#include <hip/hip_runtime.h>
#include <cstdint>

// ---------------- types / helpers ----------------
using bf16 = __bf16;
typedef __bf16 bf16x8 __attribute__((ext_vector_type(8)));
typedef float  f32x4  __attribute__((ext_vector_type(4)));

__device__ inline f32x4 mfma16(bf16x8 a, bf16x8 b, f32x4 c) {
  return __builtin_amdgcn_mfma_f32_16x16x32_bf16(a, b, c, 0, 0, 0);
}
__device__ inline float b2f(unsigned short h) {
  unsigned u = ((unsigned)h) << 16;
  return __builtin_bit_cast(float, u);
}
__device__ inline unsigned pack2(float x, float y) {
  return (unsigned)__builtin_bit_cast(unsigned short, (bf16)x)
       | ((unsigned)__builtin_bit_cast(unsigned short, (bf16)y) << 16);
}
__device__ inline void gload16(const void* g, void* l) {
  __builtin_amdgcn_global_load_lds(
      (const __attribute__((address_space(1))) void*)g,
      (__attribute__((address_space(3))) void*)l, 16, 0, 0);
}

#define BATCH 32
#define LTOK  2048
#define HWTOK 1024
#define CDIM  512
#define SM_SCALE 0.044194173824159216f   // 512^-0.5

// ---------------- 256x256 GEMM, 2-deep counted-vmcnt pipeline (T3+T4) -----
// out[M][N] = A[M][K] @ B[N][K]^T -> bf16. BM=BN=256, BK=64, 512 thr
// (8 waves 2M x 4N). LDS 128 KiB (2 dbuf). The r12 version drained vmcnt(0)
// at every barrier (T4 lesson m218: drain0 == no pipeline). This version
// keeps 2 tiles in flight and waits vmcnt(8) for loads issued a FULL
// K-iteration earlier -> near-zero stall. Never vmcnt(0) in the loop.
// Race audit: barrier#1 separates COMPUTE(buf) readers from STAGE overwrite;
// per-wave vmcnt(8) before barrier#2 => after it, ALL waves' next-tile loads
// landed; the async-written buffer is never the one read next iteration.
// Registers: r12-measured VGPR=120, no spill (schedule reorder only).
template<int BIAS, bool CONCAT, int SMODE>
__global__ __launch_bounds__(512, 2) void gemm256(
    const bf16* __restrict__ A, const bf16* __restrict__ A2,
    const bf16* __restrict__ Bm, const float* __restrict__ bias,
    bf16* __restrict__ out,
    int N, int K, long bA, long bB, long bO, int nx, int ny)
{
  // ---- bijective XCD chunk remap (m204) ----
  int nwg = gridDim.x, orig = blockIdx.x;
  int q = nwg >> 3, r = nwg & 7;
  int xcd = orig & 7, idx = orig >> 3;
  int wgid = (xcd < r ? xcd * (q + 1) : r * (q + 1) + (xcd - r) * q) + idx;
  int n0 = (wgid % nx) * 256;
  int t2 = wgid / nx;
  int m0 = (t2 % ny) * 256;
  int bz = t2 / ny;

  int tid = threadIdx.x, lane = tid & 63;
  int wid = tid >> 6, lr = lane & 15, lg = lane >> 4;
  int wm = (wid >> 2) * 128, wn = (wid & 3) * 64;   // 2M x 4N waves
  __shared__ __align__(16) bf16 lA[2][256 * 64];    // 2 x 32 KiB
  __shared__ __align__(16) bf16 lB[2][256 * 64];    // 2 x 32 KiB
  const bf16* Ab = A + (long)bz * bA;
  const bf16* Bb = Bm + (long)bz * bB;
  f32x4 acc[8][4] = {};

  int rA  = tid >> 3;               // 0..63; row = c*64 + rA
  int k8  = tid & 7;
  int k8s = k8 ^ (rA & 7);          // source pre-swizzle
  int sx  = (lr & 7) << 3;          // read-side elem XOR

  auto STAGE = [&](int b, int k0) { // 8 gload_lds (vmcnt +8)
    #pragma unroll
    for (int c = 0; c < 4; c++) {
      int row = c * 64 + rA;
      const bf16* g;
      if constexpr (CONCAT) {
        int kg = k0 + k8s * 8;
        g = (kg < 512) ? (A  + ((long)(m0 + row) << 9) + kg)
                       : (A2 + ((long)(m0 + row) << 9) + (kg - 512));
      } else {
        g = Ab + (long)(m0 + row) * K + k0 + k8s * 8;
      }
      gload16(g, (char*)lA[b] + (c * 512 + tid) * 16);
    }
    #pragma unroll
    for (int c = 0; c < 4; c++) {
      int row = c * 64 + rA;
      gload16(Bb + (long)(n0 + row) * K + k0 + k8s * 8,
              (char*)lB[b] + (c * 512 + tid) * 16);
    }
  };
  auto COMPUTE = [&](int b) {
    #pragma unroll
    for (int ss = 0; ss < 2; ss++) {
      int co = (ss * 32 + lg * 8) ^ sx;
      bf16x8 af[8], bg[4];
      #pragma unroll
      for (int t = 0; t < 8; t++)
        af[t] = *(const bf16x8*)&lA[b][(wm + t * 16 + lr) * 64 + co];
      #pragma unroll
      for (int t = 0; t < 4; t++)
        bg[t] = *(const bf16x8*)&lB[b][(wn + t * 16 + lr) * 64 + co];
      #pragma unroll
      for (int fm = 0; fm < 8; fm++)
        #pragma unroll
        for (int fn = 0; fn < 4; fn++)
          acc[fm][fn] = mfma16(af[fm], bg[fn], acc[fm][fn]);
    }
  };

  int nt = K >> 6;                  // 8 (K=512) or 16 (K=1024)
  STAGE(0, 0);
  STAGE(1, 64);                     // 16 loads in flight
  asm volatile("s_waitcnt vmcnt(8)" ::: "memory");   // tile0 landed
  __builtin_amdgcn_sched_barrier(0);
  __builtin_amdgcn_s_barrier();
  for (int t = 0; t < nt - 2; t++) {
    COMPUTE(t & 1);                 // tile t (resident)
    __builtin_amdgcn_s_barrier();   // all readers done with buf t&1
    STAGE(t & 1, (t + 2) * 64);     // overwrite it with tile t+2 (async)
    asm volatile("s_waitcnt vmcnt(8)" ::: "memory"); // tile t+1 landed
    __builtin_amdgcn_sched_barrier(0);
    __builtin_amdgcn_s_barrier();
  }
  COMPUTE(nt & 1);                  // tile nt-2  ((nt-2)&1 == nt&1)
  asm volatile("s_waitcnt vmcnt(0)" ::: "memory");   // tile nt-1 landed
  __builtin_amdgcn_sched_barrier(0);
  __builtin_amdgcn_s_barrier();
  COMPUTE((nt - 1) & 1);            // tile nt-1

  long obase = (long)bz * bO;
  #pragma unroll
  for (int fm = 0; fm < 8; fm++) {
    #pragma unroll
    for (int i = 0; i < 4; i++) {
      int row = m0 + wm + fm * 16 + lg * 4 + i;
      long rb = obase + (long)row * N;
      #pragma unroll
      for (int fn = 0; fn < 4; fn++) {
        int col = n0 + wn + fn * 16 + lr;
        if constexpr (SMODE == 1) {
          out[rb + col] = (bf16)__expf(acc[fm][fn][i] * SM_SCALE);
        } else {
          float v = acc[fm][fn][i];
          if constexpr (BIAS == 1) v += bias[col];
          if constexpr (BIAS == 2) v += bias[row];
          out[rb + col] = (bf16)v;
        }
      }
    }
  }
}

// ---------------- 128x128 proven core (kept for PV / SMODE2) --------------
template<int BIAS, bool CONCAT, int SMODE>
__global__ __launch_bounds__(256, 4) void gemm_bt(
    const bf16* __restrict__ A, const bf16* __restrict__ A2,
    const bf16* __restrict__ Bm, const float* __restrict__ bias,
    const bf16* __restrict__ resid, bf16* __restrict__ out,
    int N, int K, long bA, long bB, long bO, int nx, int ny)
{
  int nwg = gridDim.x, orig = blockIdx.x;
  int q = nwg >> 3, r = nwg & 7;
  int xcd = orig & 7, idx = orig >> 3;
  int wgid = (xcd < r ? xcd * (q + 1) : r * (q + 1) + (xcd - r) * q) + idx;
  int n0 = (wgid % nx) * 128;
  int t2 = wgid / nx;
  int m0 = (t2 % ny) * 128;
  int bz = t2 / ny;

  int tid = threadIdx.x, lane = tid & 63;
  int wid = tid >> 6, lr = lane & 15, lg = lane >> 4;
  int wm = (wid >> 1) * 64, wn = (wid & 1) * 64;
  __shared__ __align__(16) bf16 lA[128 * 64];
  __shared__ __align__(16) bf16 lB[128 * 64];
  const bf16* Ab = A + (long)bz * bA;
  const bf16* Bb = Bm + (long)bz * bB;
  f32x4 acc[4][4] = {};
  f32x4 rs[4] = {};
  bf16x8 onesf;
  #pragma unroll
  for (int j = 0; j < 8; j++) onesf[j] = (bf16)1.0f;

  int rA  = tid >> 3;
  int k8  = tid & 7;
  int k8s = k8 ^ (rA & 7);
  int sx  = (lr & 7) << 3;

  for (int k0 = 0; k0 < K; k0 += 64) {
    #pragma unroll
    for (int c = 0; c < 4; c++) {
      int row = c * 32 + rA;
      const bf16* g;
      if constexpr (CONCAT) {
        int kg = k0 + k8s * 8;
        g = (kg < 512) ? (A  + ((long)(m0 + row) << 9) + kg)
                       : (A2 + ((long)(m0 + row) << 9) + (kg - 512));
      } else {
        g = Ab + (long)(m0 + row) * K + k0 + k8s * 8;
      }
      gload16(g, (char*)lA + (c * 256 + tid) * 16);
    }
    #pragma unroll
    for (int c = 0; c < 4; c++) {
      int row = c * 32 + rA;
      gload16(Bb + (long)(n0 + row) * K + k0 + k8s * 8,
              (char*)lB + (c * 256 + tid) * 16);
    }
    __syncthreads();
    #pragma unroll
    for (int ss = 0; ss < 2; ss++) {
      int co = (ss * 32 + lg * 8) ^ sx;
      bf16x8 af[4], bg[4];
      #pragma unroll
      for (int t = 0; t < 4; t++)
        af[t] = *(const bf16x8*)&lA[(wm + t * 16 + lr) * 64 + co];
      #pragma unroll
      for (int t = 0; t < 4; t++)
        bg[t] = *(const bf16x8*)&lB[(wn + t * 16 + lr) * 64 + co];
      #pragma unroll
      for (int fm = 0; fm < 4; fm++)
        #pragma unroll
        for (int fn = 0; fn < 4; fn++)
          acc[fm][fn] = mfma16(af[fm], bg[fn], acc[fm][fn]);
      if constexpr (SMODE == 2) {
        #pragma unroll
        for (int fm = 0; fm < 4; fm++)
          rs[fm] = mfma16(af[fm], onesf, rs[fm]);
      }
    }
    __syncthreads();
  }

  long obase = (long)bz * bO;
  #pragma unroll
  for (int fm = 0; fm < 4; fm++) {
    #pragma unroll
    for (int i = 0; i < 4; i++) {
      int row = m0 + wm + fm * 16 + lg * 4 + i;
      long rb = obase + (long)row * N;
      float inv;
      if constexpr (SMODE == 2) inv = 1.0f / rs[fm][i];
      #pragma unroll
      for (int fn = 0; fn < 4; fn++) {
        int col = n0 + wn + fn * 16 + lr;
        if constexpr (SMODE == 1) {
          out[rb + col] = (bf16)__expf(acc[fm][fn][i] * SM_SCALE);
        } else if constexpr (SMODE == 2) {
          float v = acc[fm][fn][i] * inv + (float)resid[rb + col];
          out[rb + col] = (bf16)v;
        } else {
          float v = acc[fm][fn][i];
          if constexpr (BIAS == 1) v += bias[col];
          if constexpr (BIAS == 2) v += bias[row];
          out[rb + col] = (bf16)v;
        }
      }
    }
  }
}

// ---------------- elementwise f32 -> bf16 ---------------------------------
__global__ __launch_bounds__(256) void cvt_k(const float* __restrict__ in,
                                             bf16* __restrict__ out)
{
  long i = ((long)blockIdx.x * 256 + threadIdx.x) * 8;
  float4 a = *(const float4*)(in + i);
  float4 c = *(const float4*)(in + i + 4);
  unsigned o[4];
  o[0] = pack2(a.x, a.y); o[1] = pack2(a.z, a.w);
  o[2] = pack2(c.x, c.y); o[3] = pack2(c.z, c.w);
  *(uint4*)(out + i) = *(uint4*)o;
}

// ---------------- transpose + convert: in[rows][cols] f32 -> out[cols][rows] bf16
__global__ __launch_bounds__(256) void cvtT_k(const float* __restrict__ in,
                                              bf16* __restrict__ out,
                                              int rows, int cols, long bElems)
{
  int bz = blockIdx.z;
  int c0 = blockIdx.x * 64, r0 = blockIdx.y * 64;
  const float* I = in + (long)bz * bElems;
  bf16* O = out + (long)bz * bElems;
  __shared__ __align__(16) bf16 t[64][72];
  int tid = threadIdx.x;
  #pragma unroll
  for (int j = 0; j < 4; j++) {
    int kk = j * 16 + (tid >> 4);
    int mm = (tid & 15) * 4;
    float4 v = *(const float4*)(I + (long)(r0 + kk) * cols + c0 + mm);
    t[mm + 0][kk] = (bf16)v.x; t[mm + 1][kk] = (bf16)v.y;
    t[mm + 2][kk] = (bf16)v.z; t[mm + 3][kk] = (bf16)v.w;
  }
  __syncthreads();
  #pragma unroll
  for (int p = 0; p < 2; p++) {
    int r = (tid >> 3) + p * 32;
    int c8 = tid & 7;
    *(uint4*)(O + (long)(c0 + r) * rows + r0 + c8 * 8) = *(const uint4*)&t[r][c8 * 8];
  }
}

// ---------------- 5 weight transposes (512x512) in one dispatch -----------
__global__ __launch_bounds__(256) void cvtT5_k(const float* __restrict__ p0,
                                               const float* __restrict__ p1,
                                               const float* __restrict__ p2,
                                               const float* __restrict__ p3,
                                               const float* __restrict__ p4,
                                               bf16* __restrict__ out)
{
  int z = blockIdx.z;
  const float* I = z == 0 ? p0 : z == 1 ? p1 : z == 2 ? p2 : z == 3 ? p3 : p4;
  bf16* O = out + (long)z * 262144;
  int c0 = blockIdx.x * 64, r0 = blockIdx.y * 64;
  __shared__ __align__(16) bf16 t[64][72];
  int tid = threadIdx.x;
  #pragma unroll
  for (int j = 0; j < 4; j++) {
    int kk = j * 16 + (tid >> 4);
    int mm = (tid & 15) * 4;
    float4 v = *(const float4*)(I + (long)(r0 + kk) * 512 + c0 + mm);
    t[mm + 0][kk] = (bf16)v.x; t[mm + 1][kk] = (bf16)v.y;
    t[mm + 2][kk] = (bf16)v.z; t[mm + 3][kk] = (bf16)v.w;
  }
  __syncthreads();
  #pragma unroll
  for (int p = 0; p < 2; p++) {
    int r = (tid >> 3) + p * 32;
    int c8 = tid & 7;
    *(uint4*)(O + (long)(c0 + r) * 512 + r0 + c8 * 8) = *(const uint4*)&t[r][c8 * 8];
  }
}

// ---------------- row LayerNorm over 512 bf16, in place -------------------
__global__ __launch_bounds__(256) void ln_k(bf16* __restrict__ T,
                                            const float* __restrict__ g,
                                            const float* __restrict__ b)
{
  int r = blockIdx.x * 4 + (threadIdx.x >> 6);
  int lane = threadIdx.x & 63;
  bf16* row = T + (long)r * 512 + lane * 8;
  uint4 u = *(const uint4*)row;
  float v[8];
  {
    unsigned* up = (unsigned*)&u;
    #pragma unroll
    for (int e = 0; e < 4; e++) { v[2*e] = b2f(up[e] & 0xffff); v[2*e+1] = b2f(up[e] >> 16); }
  }
  float s = 0.f, s2 = 0.f;
  #pragma unroll
  for (int j = 0; j < 8; j++) { s += v[j]; s2 += v[j] * v[j]; }
  #pragma unroll
  for (int k = 1; k < 64; k <<= 1) { s += __shfl_xor(s, k); s2 += __shfl_xor(s2, k); }
  float mu = s * (1.0f / 512.0f);
  float var = s2 * (1.0f / 512.0f) - mu * mu;
  float rsq = rsqrtf(var + 1e-5f);
  float4 g0 = *(const float4*)(g + lane * 8);
  float4 g1 = *(const float4*)(g + lane * 8 + 4);
  float4 b0 = *(const float4*)(b + lane * 8);
  float4 b1 = *(const float4*)(b + lane * 8 + 4);
  float gg[8] = {g0.x,g0.y,g0.z,g0.w,g1.x,g1.y,g1.z,g1.w};
  float bb[8] = {b0.x,b0.y,b0.z,b0.w,b1.x,b1.y,b1.z,b1.w};
  unsigned o[4];
  #pragma unroll
  for (int e = 0; e < 4; e++)
    o[e] = pack2((v[2*e]   - mu) * rsq * gg[2*e]   + bb[2*e],
                 (v[2*e+1] - mu) * rsq * gg[2*e+1] + bb[2*e+1]);
  *(uint4*)row = *(uint4*)o;
}

// ---------------- BatchNorm stats / finalize / apply ----------------------
__global__ __launch_bounds__(256) void bn_stats_k(const bf16* __restrict__ Y,
                                                  float* __restrict__ sums)
{
  long r0 = (long)blockIdx.x * 256; int t = threadIdx.x;
  float s0 = 0, s1 = 0, q0 = 0, q1 = 0;
  for (int j = 0; j < 256; j++) {
    unsigned u = *(const unsigned*)(Y + (r0 + j) * 512 + t * 2);
    float a = b2f((unsigned short)(u & 0xffff));
    float c = b2f((unsigned short)(u >> 16));
    s0 += a; q0 += a * a; s1 += c; q1 += c * c;
  }
  atomicAdd(&sums[t * 2],           s0);
  atomicAdd(&sums[t * 2 + 1],       s1);
  atomicAdd(&sums[512 + t * 2],     q0);
  atomicAdd(&sums[512 + t * 2 + 1], q1);
}

__global__ void bn_finalize_k(const float* __restrict__ sums,
                              const float* __restrict__ bn_g,
                              const float* __restrict__ bn_b,
                              float* __restrict__ ss)
{
  int c = threadIdx.x;   // 512
  const float invN = 1.0f / 65536.0f;
  float mean = sums[c] * invN;
  float var  = sums[512 + c] * invN - mean * mean;
  float sc = bn_g[c] * rsqrtf(var + 1e-5f);
  ss[c] = sc;
  ss[512 + c] = bn_b[c] - mean * sc;
}

__global__ __launch_bounds__(256) void bn_apply_k(const bf16* __restrict__ Y,
                                                  const float* __restrict__ ss,
                                                  float* __restrict__ out)
{
  long idx = ((long)blockIdx.x * 256 + threadIdx.x) * 8;
  int c0 = (int)(idx & 511);
  uint4 u = *(const uint4*)(Y + idx);
  const unsigned* up = (const unsigned*)&u;
  float4 sa = *(const float4*)(ss + c0);
  float4 sb = *(const float4*)(ss + c0 + 4);
  float4 ha = *(const float4*)(ss + 512 + c0);
  float4 hb = *(const float4*)(ss + 512 + c0 + 4);
  float f[8];
  #pragma unroll
  for (int e = 0; e < 4; e++) {
    f[2 * e]     = b2f((unsigned short)(up[e] & 0xffff));
    f[2 * e + 1] = b2f((unsigned short)(up[e] >> 16));
  }
  float4 o0, o1;
  o0.x = fmaxf(0.f, f[0] * sa.x + ha.x);
  o0.y = fmaxf(0.f, f[1] * sa.y + ha.y);
  o0.z = fmaxf(0.f, f[2] * sa.z + ha.z);
  o0.w = fmaxf(0.f, f[3] * sa.w + ha.w);
  o1.x = fmaxf(0.f, f[4] * sb.x + hb.x);
  o1.y = fmaxf(0.f, f[5] * sb.y + hb.y);
  o1.z = fmaxf(0.f, f[6] * sb.z + hb.z);
  o1.w = fmaxf(0.f, f[7] * sb.w + hb.w);
  *(float4*)(out + idx) = o0;
  *(float4*)(out + idx + 4) = o1;
}

// ---------------- launch ---------------------------------------------------
extern "C" void kernel_launch(void* const* d_in, const int* in_sizes, int n_in,
                              void* d_out, int out_size, void* d_ws, size_t ws_size,
                              hipStream_t stream)
{
  (void)in_sizes; (void)n_in; (void)out_size; (void)ws_size;
  const float* Fj  = (const float*)d_in[0];
  const float* Fs  = (const float*)d_in[1];
  const float* Fe  = (const float*)d_in[2];
  const float* Wq  = (const float*)d_in[3];
  const float* bq  = (const float*)d_in[4];
  const float* Wsk = (const float*)d_in[5];
  const float* bsk = (const float*)d_in[6];
  const float* Wsv = (const float*)d_in[7];
  const float* bsv = (const float*)d_in[8];
  const float* Wek = (const float*)d_in[9];
  const float* bek = (const float*)d_in[10];
  const float* Wev = (const float*)d_in[11];
  const float* bev = (const float*)d_in[12];
  const float* lng = (const float*)d_in[13];
  const float* lnb = (const float*)d_in[14];
  const float* Wf  = (const float*)d_in[15];
  const float* bfp = (const float*)d_in[16];
  const float* bng = (const float*)d_in[17];
  const float* bnb = (const float*)d_in[18];

  char* ws = (char*)d_ws;
  // ws map: FjB/T2 0-64MiB | Qb/Yb 64-128 | Kb 128-160 | Vt 160-192 |
  //         weights 192-195.5 | stats. Peak ~196 MiB.
  // d_out (128 MiB): T1 bf16 lower half; upper half = FT then P' (strictly
  // sequential on stream: FT consumed by K/Vt before S overwrites).
  bf16* FjB = (bf16*)(ws);
  bf16* T2  = FjB;                              // attn-1 PV aliases (same-elem)
  bf16* Qb  = (bf16*)(ws + 67108864L);
  bf16* Yb  = Qb;
  bf16* Kb  = (bf16*)(ws + 134217728L);         // 32 MiB K full
  bf16* Vt  = (bf16*)(ws + 167772160L);         // 32 MiB Vt full
  bf16* Wt5 = (bf16*)(ws + 201326592L);         // 5 x 512 KiB weights^T
  bf16* WfB = (bf16*)(ws + 203948032L);         // 1 MiB
  float* stats = (float*)(ws + 204996608L);
  float* ssbuf = (float*)(ws + 205000704L);
  bf16* T1  = (bf16*)d_out;
  bf16* FT  = (bf16*)((char*)d_out + 67108864L);
  bf16* Rg  = FT;                               // P' (64 MiB, 16 batches)
  float* outp = (float*)d_out;

  const long PB_Q  = (long)LTOK * CDIM;      // 1048576
  const long PB_KV = (long)HWTOK * CDIM;     // 524288
  const long PB_S  = (long)LTOK * HWTOK;     // 2097152

  dim3 blk(256), gblk(512);

  // --- conversions (weights + Fj) ---
  cvt_k<<<dim3(16384), blk, 0, stream>>>(Fj, FjB);
  cvt_k<<<dim3(256),   blk, 0, stream>>>(Wf, WfB);
  cvtT5_k<<<dim3(8, 8, 5), blk, 0, stream>>>(Wq, Wsk, Wsv, Wek, Wev, Wt5);

  // --- Q projection: M=65536 N=512 K=512 (256^2 counted-vmcnt kernel) ---
  gemm256<1,false,0><<<dim3(512), gblk, 0, stream>>>(
      FjB, nullptr, Wt5, bq, Qb, 512, 512, 0, 0, 0, 2, 256);

  for (int attn = 0; attn < 2; attn++) {
    const float* Fsrc = attn ? Fe : Fs;
    const bf16* WkT = Wt5 + (attn ? 786432 : 262144);
    const bf16* WvT = Wt5 + (attn ? 1048576 : 524288);
    const float* bk = attn ? bek : bsk;
    const float* bv = attn ? bev : bsv;
    bf16* Tout = attn ? T2 : T1;

    // FT[b][m][c] (bf16, d_out upper half) = transpose of Fsrc [b][c][m]
    cvtT_k<<<dim3(16, 8, 32), blk, 0, stream>>>(Fsrc, FT, 512, 1024, PB_KV);

    // K full: per-batch M=1024 N=512 K=512
    gemm256<1,false,0><<<dim3(256), gblk, 0, stream>>>(
        FT, nullptr, WkT, bk, Kb, 512, 512, PB_KV, 0, PB_KV, 2, 4);
    // Vt full: per-batch M=512 N=1024 K=512 (A = WvT, B = FT, row bias)
    gemm256<2,false,0><<<dim3(256), gblk, 0, stream>>>(
        WvT, nullptr, FT, bv, Vt, 1024, 512, 0, PB_KV, PB_KV, 4, 2);

    for (int c = 0; c < 2; c++) {          // 16-batch chunks
      int b0 = c * 16;
      // P' = exp(scale * Q K^T): per-batch M=2048 N=1024 K=512
      gemm256<0,false,1><<<dim3(512), gblk, 0, stream>>>(
          Qb + (long)b0 * PB_Q, nullptr, Kb + (long)b0 * PB_KV,
          nullptr, Rg, 1024, 512, PB_Q, PB_KV, PB_S, 4, 8);
      // T = P'V / rowsum + Fj: per-batch M=2048 N=512 K=1024 (128^2 proven)
      gemm_bt<0,false,2><<<dim3(1024), blk, 0, stream>>>(
          Rg, nullptr, Vt + (long)b0 * PB_KV, nullptr,
          FjB + (long)b0 * PB_Q, Tout + (long)b0 * PB_Q,
          512, 1024, PB_S, PB_KV, PB_Q, 4, 16);
    }
    ln_k<<<dim3(16384), blk, 0, stream>>>(Tout, lng, lnb);
  }

  // --- fusion conv1d: Y = [T1|T2] @ Wf^T + bf (M=65536 N=512 K=1024) ---
  gemm256<1,true,0><<<dim3(512), gblk, 0, stream>>>(
      T1, T2, WfB, bfp, Yb, 512, 1024, 0, 0, 0, 2, 256);

  // --- BatchNorm (train stats) + ReLU -> f32 out ---
  (void)hipMemsetAsync(stats, 0, 4096, stream);
  bn_stats_k<<<dim3(256), blk, 0, stream>>>(Yb, stats);
  bn_finalize_k<<<dim3(1), dim3(512), 0, stream>>>(stats, bng, bnb, ssbuf);
  bn_apply_k<<<dim3(16384), blk, 0, stream>>>(Yb, ssbuf, outp);
}

// Round 14
// 837.828 us; speedup vs baseline: 1.0729x; 1.0202x over previous
//
#include <hip/hip_runtime.h>
#include <cstdint>

// ---------------- types / helpers ----------------
using bf16 = __bf16;
typedef __bf16 bf16x8 __attribute__((ext_vector_type(8)));
typedef float  f32x4  __attribute__((ext_vector_type(4)));

__device__ inline f32x4 mfma16(bf16x8 a, bf16x8 b, f32x4 c) {
  return __builtin_amdgcn_mfma_f32_16x16x32_bf16(a, b, c, 0, 0, 0);
}
__device__ inline float b2f(unsigned short h) {
  unsigned u = ((unsigned)h) << 16;
  return __builtin_bit_cast(float, u);
}
__device__ inline unsigned pack2(float x, float y) {
  return (unsigned)__builtin_bit_cast(unsigned short, (bf16)x)
       | ((unsigned)__builtin_bit_cast(unsigned short, (bf16)y) << 16);
}
__device__ inline void gload16(const void* g, void* l) {
  __builtin_amdgcn_global_load_lds(
      (const __attribute__((address_space(1))) void*)g,
      (__attribute__((address_space(3))) void*)l, 16, 0, 0);
}

#define BATCH 32
#define LTOK  2048
#define HWTOK 1024
#define CDIM  512
#define SM_SCALE 0.044194173824159216f   // 512^-0.5

// ---------------- universal bf16 GEMM (proven core, session-best r11) -----
// out[M][N] = A[M][K] @ B[N][K]^T -> bf16. 128x128 tile, BK=64, 256 thr
// (4 waves 2x2). m97 single-buffer 2-barrier loop; XOR swizzle both-sides
// (conflicts=0 measured); bijective XCD remap (FETCH=ideal measured).
// LB=4 is the occupancy max: unified VGPR+acc footprint ~112/wave; LB=5
// (cap ~96) spilled (r10); 256^2 structures slower on these shapes (r12/13).
// SMODE: 0 bias (BIAS 1=col 2=row), 1 exp-epilogue, 2 rowsum+bf16-resid.
template<int BIAS, bool CONCAT, int SMODE>
__global__ __launch_bounds__(256, 4) void gemm_bt(
    const bf16* __restrict__ A, const bf16* __restrict__ A2,
    const bf16* __restrict__ Bm, const float* __restrict__ bias,
    const bf16* __restrict__ resid, bf16* __restrict__ out,
    int N, int K, long bA, long bB, long bO, int nx, int ny)
{
  // ---- bijective XCD chunk remap (m204) ----
  int nwg = gridDim.x, orig = blockIdx.x;
  int q = nwg >> 3, r = nwg & 7;
  int xcd = orig & 7, idx = orig >> 3;
  int wgid = (xcd < r ? xcd * (q + 1) : r * (q + 1) + (xcd - r) * q) + idx;
  int n0 = (wgid % nx) * 128;
  int t2 = wgid / nx;
  int m0 = (t2 % ny) * 128;
  int bz = t2 / ny;

  int tid = threadIdx.x, lane = tid & 63;
  int wid = tid >> 6, lr = lane & 15, lg = lane >> 4;
  int wm = (wid >> 1) * 64, wn = (wid & 1) * 64;
  __shared__ __align__(16) bf16 lA[128 * 64];
  __shared__ __align__(16) bf16 lB[128 * 64];
  const bf16* Ab = A + (long)bz * bA;
  const bf16* Bb = Bm + (long)bz * bB;
  f32x4 acc[4][4] = {};
  f32x4 rs[4] = {};                 // SMODE==2 rowsums
  bf16x8 onesf;
  #pragma unroll
  for (int j = 0; j < 8; j++) onesf[j] = (bf16)1.0f;

  int rA  = tid >> 3;               // row = c*32 + rA
  int k8  = tid & 7;
  int k8s = k8 ^ (rA & 7);          // source pre-swizzle
  int sx  = (lr & 7) << 3;          // read-side elem XOR

  for (int k0 = 0; k0 < K; k0 += 64) {
    #pragma unroll
    for (int c = 0; c < 4; c++) {
      int row = c * 32 + rA;
      const bf16* g;
      if constexpr (CONCAT) {
        int kg = k0 + k8s * 8;
        g = (kg < 512) ? (A  + ((long)(m0 + row) << 9) + kg)
                       : (A2 + ((long)(m0 + row) << 9) + (kg - 512));
      } else {
        g = Ab + (long)(m0 + row) * K + k0 + k8s * 8;
      }
      gload16(g, (char*)lA + (c * 256 + tid) * 16);
    }
    #pragma unroll
    for (int c = 0; c < 4; c++) {
      int row = c * 32 + rA;
      gload16(Bb + (long)(n0 + row) * K + k0 + k8s * 8,
              (char*)lB + (c * 256 + tid) * 16);
    }
    __syncthreads();
    #pragma unroll
    for (int ss = 0; ss < 2; ss++) {
      int co = (ss * 32 + lg * 8) ^ sx;
      bf16x8 af[4], bg[4];
      #pragma unroll
      for (int t = 0; t < 4; t++)
        af[t] = *(const bf16x8*)&lA[(wm + t * 16 + lr) * 64 + co];
      #pragma unroll
      for (int t = 0; t < 4; t++)
        bg[t] = *(const bf16x8*)&lB[(wn + t * 16 + lr) * 64 + co];
      #pragma unroll
      for (int fm = 0; fm < 4; fm++)
        #pragma unroll
        for (int fn = 0; fn < 4; fn++)
          acc[fm][fn] = mfma16(af[fm], bg[fn], acc[fm][fn]);
      if constexpr (SMODE == 2) {
        #pragma unroll
        for (int fm = 0; fm < 4; fm++)
          rs[fm] = mfma16(af[fm], onesf, rs[fm]);
      }
    }
    __syncthreads();
  }

  long obase = (long)bz * bO;
  #pragma unroll
  for (int fm = 0; fm < 4; fm++) {
    #pragma unroll
    for (int i = 0; i < 4; i++) {
      int row = m0 + wm + fm * 16 + lg * 4 + i;
      long rb = obase + (long)row * N;
      float inv;
      if constexpr (SMODE == 2) inv = 1.0f / rs[fm][i];
      #pragma unroll
      for (int fn = 0; fn < 4; fn++) {
        int col = n0 + wn + fn * 16 + lr;
        if constexpr (SMODE == 1) {
          out[rb + col] = (bf16)__expf(acc[fm][fn][i] * SM_SCALE);
        } else if constexpr (SMODE == 2) {
          float v = acc[fm][fn][i] * inv + (float)resid[rb + col];
          out[rb + col] = (bf16)v;
        } else {
          float v = acc[fm][fn][i];
          if constexpr (BIAS == 1) v += bias[col];
          if constexpr (BIAS == 2) v += bias[row];
          out[rb + col] = (bf16)v;
        }
      }
    }
  }
}

// ---------------- elementwise f32 -> bf16 ---------------------------------
__global__ __launch_bounds__(256) void cvt_k(const float* __restrict__ in,
                                             bf16* __restrict__ out)
{
  long i = ((long)blockIdx.x * 256 + threadIdx.x) * 8;
  float4 a = *(const float4*)(in + i);
  float4 c = *(const float4*)(in + i + 4);
  unsigned o[4];
  o[0] = pack2(a.x, a.y); o[1] = pack2(a.z, a.w);
  o[2] = pack2(c.x, c.y); o[3] = pack2(c.z, c.w);
  *(uint4*)(out + i) = *(uint4*)o;
}

// ---------------- transpose + convert: in[rows][cols] f32 -> out[cols][rows] bf16
__global__ __launch_bounds__(256) void cvtT_k(const float* __restrict__ in,
                                              bf16* __restrict__ out,
                                              int rows, int cols, long bElems)
{
  int bz = blockIdx.z;
  int c0 = blockIdx.x * 64, r0 = blockIdx.y * 64;
  const float* I = in + (long)bz * bElems;
  bf16* O = out + (long)bz * bElems;
  __shared__ __align__(16) bf16 t[64][72];
  int tid = threadIdx.x;
  #pragma unroll
  for (int j = 0; j < 4; j++) {
    int kk = j * 16 + (tid >> 4);
    int mm = (tid & 15) * 4;
    float4 v = *(const float4*)(I + (long)(r0 + kk) * cols + c0 + mm);
    t[mm + 0][kk] = (bf16)v.x; t[mm + 1][kk] = (bf16)v.y;
    t[mm + 2][kk] = (bf16)v.z; t[mm + 3][kk] = (bf16)v.w;
  }
  __syncthreads();
  #pragma unroll
  for (int p = 0; p < 2; p++) {
    int r = (tid >> 3) + p * 32;
    int c8 = tid & 7;
    *(uint4*)(O + (long)(c0 + r) * rows + r0 + c8 * 8) = *(const uint4*)&t[r][c8 * 8];
  }
}

// ---------------- 5 weight transposes (512x512) in one dispatch -----------
__global__ __launch_bounds__(256) void cvtT5_k(const float* __restrict__ p0,
                                               const float* __restrict__ p1,
                                               const float* __restrict__ p2,
                                               const float* __restrict__ p3,
                                               const float* __restrict__ p4,
                                               bf16* __restrict__ out)
{
  int z = blockIdx.z;
  const float* I = z == 0 ? p0 : z == 1 ? p1 : z == 2 ? p2 : z == 3 ? p3 : p4;
  bf16* O = out + (long)z * 262144;
  int c0 = blockIdx.x * 64, r0 = blockIdx.y * 64;
  __shared__ __align__(16) bf16 t[64][72];
  int tid = threadIdx.x;
  #pragma unroll
  for (int j = 0; j < 4; j++) {
    int kk = j * 16 + (tid >> 4);
    int mm = (tid & 15) * 4;
    float4 v = *(const float4*)(I + (long)(r0 + kk) * 512 + c0 + mm);
    t[mm + 0][kk] = (bf16)v.x; t[mm + 1][kk] = (bf16)v.y;
    t[mm + 2][kk] = (bf16)v.z; t[mm + 3][kk] = (bf16)v.w;
  }
  __syncthreads();
  #pragma unroll
  for (int p = 0; p < 2; p++) {
    int r = (tid >> 3) + p * 32;
    int c8 = tid & 7;
    *(uint4*)(O + (long)(c0 + r) * 512 + r0 + c8 * 8) = *(const uint4*)&t[r][c8 * 8];
  }
}

// ---------------- row LayerNorm over 512 bf16, in place -------------------
__global__ __launch_bounds__(256) void ln_k(bf16* __restrict__ T,
                                            const float* __restrict__ g,
                                            const float* __restrict__ b)
{
  int r = blockIdx.x * 4 + (threadIdx.x >> 6);
  int lane = threadIdx.x & 63;
  bf16* row = T + (long)r * 512 + lane * 8;
  uint4 u = *(const uint4*)row;
  float v[8];
  {
    unsigned* up = (unsigned*)&u;
    #pragma unroll
    for (int e = 0; e < 4; e++) { v[2*e] = b2f(up[e] & 0xffff); v[2*e+1] = b2f(up[e] >> 16); }
  }
  float s = 0.f, s2 = 0.f;
  #pragma unroll
  for (int j = 0; j < 8; j++) { s += v[j]; s2 += v[j] * v[j]; }
  #pragma unroll
  for (int k = 1; k < 64; k <<= 1) { s += __shfl_xor(s, k); s2 += __shfl_xor(s2, k); }
  float mu = s * (1.0f / 512.0f);
  float var = s2 * (1.0f / 512.0f) - mu * mu;
  float rsq = rsqrtf(var + 1e-5f);
  float4 g0 = *(const float4*)(g + lane * 8);
  float4 g1 = *(const float4*)(g + lane * 8 + 4);
  float4 b0 = *(const float4*)(b + lane * 8);
  float4 b1 = *(const float4*)(b + lane * 8 + 4);
  float gg[8] = {g0.x,g0.y,g0.z,g0.w,g1.x,g1.y,g1.z,g1.w};
  float bb[8] = {b0.x,b0.y,b0.z,b0.w,b1.x,b1.y,b1.z,b1.w};
  unsigned o[4];
  #pragma unroll
  for (int e = 0; e < 4; e++)
    o[e] = pack2((v[2*e]   - mu) * rsq * gg[2*e]   + bb[2*e],
                 (v[2*e+1] - mu) * rsq * gg[2*e+1] + bb[2*e+1]);
  *(uint4*)row = *(uint4*)o;
}

// ---------------- BatchNorm stats / finalize / apply ----------------------
__global__ __launch_bounds__(256) void bn_stats_k(const bf16* __restrict__ Y,
                                                  float* __restrict__ sums)
{
  long r0 = (long)blockIdx.x * 256; int t = threadIdx.x;
  float s0 = 0, s1 = 0, q0 = 0, q1 = 0;
  for (int j = 0; j < 256; j++) {
    unsigned u = *(const unsigned*)(Y + (r0 + j) * 512 + t * 2);
    float a = b2f((unsigned short)(u & 0xffff));
    float c = b2f((unsigned short)(u >> 16));
    s0 += a; q0 += a * a; s1 += c; q1 += c * c;
  }
  atomicAdd(&sums[t * 2],           s0);
  atomicAdd(&sums[t * 2 + 1],       s1);
  atomicAdd(&sums[512 + t * 2],     q0);
  atomicAdd(&sums[512 + t * 2 + 1], q1);
}

__global__ void bn_finalize_k(const float* __restrict__ sums,
                              const float* __restrict__ bn_g,
                              const float* __restrict__ bn_b,
                              float* __restrict__ ss)
{
  int c = threadIdx.x;   // 512
  const float invN = 1.0f / 65536.0f;
  float mean = sums[c] * invN;
  float var  = sums[512 + c] * invN - mean * mean;
  float sc = bn_g[c] * rsqrtf(var + 1e-5f);
  ss[c] = sc;
  ss[512 + c] = bn_b[c] - mean * sc;
}

__global__ __launch_bounds__(256) void bn_apply_k(const bf16* __restrict__ Y,
                                                  const float* __restrict__ ss,
                                                  float* __restrict__ out)
{
  long idx = ((long)blockIdx.x * 256 + threadIdx.x) * 8;
  int c0 = (int)(idx & 511);
  uint4 u = *(const uint4*)(Y + idx);
  const unsigned* up = (const unsigned*)&u;
  float4 sa = *(const float4*)(ss + c0);
  float4 sb = *(const float4*)(ss + c0 + 4);
  float4 ha = *(const float4*)(ss + 512 + c0);
  float4 hb = *(const float4*)(ss + 512 + c0 + 4);
  float f[8];
  #pragma unroll
  for (int e = 0; e < 4; e++) {
    f[2 * e]     = b2f((unsigned short)(up[e] & 0xffff));
    f[2 * e + 1] = b2f((unsigned short)(up[e] >> 16));
  }
  float4 o0, o1;
  o0.x = fmaxf(0.f, f[0] * sa.x + ha.x);
  o0.y = fmaxf(0.f, f[1] * sa.y + ha.y);
  o0.z = fmaxf(0.f, f[2] * sa.z + ha.z);
  o0.w = fmaxf(0.f, f[3] * sa.w + ha.w);
  o1.x = fmaxf(0.f, f[4] * sb.x + hb.x);
  o1.y = fmaxf(0.f, f[5] * sb.y + hb.y);
  o1.z = fmaxf(0.f, f[6] * sb.z + hb.z);
  o1.w = fmaxf(0.f, f[7] * sb.w + hb.w);
  *(float4*)(out + idx) = o0;
  *(float4*)(out + idx + 4) = o1;
}

// ---------------- launch ---------------------------------------------------
extern "C" void kernel_launch(void* const* d_in, const int* in_sizes, int n_in,
                              void* d_out, int out_size, void* d_ws, size_t ws_size,
                              hipStream_t stream)
{
  (void)in_sizes; (void)n_in; (void)out_size; (void)ws_size;
  const float* Fj  = (const float*)d_in[0];
  const float* Fs  = (const float*)d_in[1];
  const float* Fe  = (const float*)d_in[2];
  const float* Wq  = (const float*)d_in[3];
  const float* bq  = (const float*)d_in[4];
  const float* Wsk = (const float*)d_in[5];
  const float* bsk = (const float*)d_in[6];
  const float* Wsv = (const float*)d_in[7];
  const float* bsv = (const float*)d_in[8];
  const float* Wek = (const float*)d_in[9];
  const float* bek = (const float*)d_in[10];
  const float* Wev = (const float*)d_in[11];
  const float* bev = (const float*)d_in[12];
  const float* lng = (const float*)d_in[13];
  const float* lnb = (const float*)d_in[14];
  const float* Wf  = (const float*)d_in[15];
  const float* bfp = (const float*)d_in[16];
  const float* bng = (const float*)d_in[17];
  const float* bnb = (const float*)d_in[18];

  char* ws = (char*)d_ws;
  // ws map: FjB/T2 0-64MiB | Qb/Yb 64-128 | Kb 128-160 | Vt 160-192 |
  //         weights 192-195.5 | stats. Peak ~196 MiB.
  // d_out (128 MiB): T1 bf16 lower half; upper half = FT then P' (strictly
  // sequential on stream: FT consumed by K/Vt before S overwrites).
  bf16* FjB = (bf16*)(ws);
  bf16* T2  = FjB;                              // attn-1 PV aliases (same-elem)
  bf16* Qb  = (bf16*)(ws + 67108864L);
  bf16* Yb  = Qb;
  bf16* Kb  = (bf16*)(ws + 134217728L);         // 32 MiB K full
  bf16* Vt  = (bf16*)(ws + 167772160L);         // 32 MiB Vt full
  bf16* Wt5 = (bf16*)(ws + 201326592L);         // 5 x 512 KiB weights^T
  bf16* WfB = (bf16*)(ws + 203948032L);         // 1 MiB
  float* stats = (float*)(ws + 204996608L);
  float* ssbuf = (float*)(ws + 205000704L);
  bf16* T1  = (bf16*)d_out;
  bf16* FT  = (bf16*)((char*)d_out + 67108864L);
  bf16* Rg  = FT;                               // P' (64 MiB, 16 batches)
  float* outp = (float*)d_out;

  const long PB_Q  = (long)LTOK * CDIM;      // 1048576
  const long PB_KV = (long)HWTOK * CDIM;     // 524288
  const long PB_S  = (long)LTOK * HWTOK;     // 2097152

  dim3 blk(256);

  // --- conversions (weights + Fj) ---
  cvt_k<<<dim3(16384), blk, 0, stream>>>(Fj, FjB);
  cvt_k<<<dim3(256),   blk, 0, stream>>>(Wf, WfB);
  cvtT5_k<<<dim3(8, 8, 5), blk, 0, stream>>>(Wq, Wsk, Wsv, Wek, Wev, Wt5);

  // --- Q projection: M=65536 N=512 K=512 ---
  gemm_bt<1,false,0><<<dim3(2048), blk, 0, stream>>>(
      FjB, nullptr, Wt5, bq, nullptr, Qb, 512, 512, 0, 0, 0, 4, 512);

  for (int attn = 0; attn < 2; attn++) {
    const float* Fsrc = attn ? Fe : Fs;
    const bf16* WkT = Wt5 + (attn ? 786432 : 262144);
    const bf16* WvT = Wt5 + (attn ? 1048576 : 524288);
    const float* bk = attn ? bek : bsk;
    const float* bv = attn ? bev : bsv;
    bf16* Tout = attn ? T2 : T1;

    // FT[b][m][c] (bf16, d_out upper half) = transpose of Fsrc [b][c][m]
    cvtT_k<<<dim3(16, 8, 32), blk, 0, stream>>>(Fsrc, FT, 512, 1024, PB_KV);

    // K full: per-batch M=1024 N=512 K=512
    gemm_bt<1,false,0><<<dim3(1024), blk, 0, stream>>>(
        FT, nullptr, WkT, bk, nullptr, Kb, 512, 512, PB_KV, 0, PB_KV, 4, 8);
    // Vt full: per-batch M=512 N=1024 K=512 (A = WvT, B = FT, row bias)
    gemm_bt<2,false,0><<<dim3(1024), blk, 0, stream>>>(
        WvT, nullptr, FT, bv, nullptr, Vt, 1024, 512, 0, PB_KV, PB_KV, 8, 4);

    for (int c = 0; c < 2; c++) {          // 16-batch chunks
      int b0 = c * 16;
      // P' = exp(scale * Q K^T): per-batch M=2048 N=1024 K=512
      gemm_bt<0,false,1><<<dim3(2048), blk, 0, stream>>>(
          Qb + (long)b0 * PB_Q, nullptr, Kb + (long)b0 * PB_KV,
          nullptr, nullptr, Rg, 1024, 512, PB_Q, PB_KV, PB_S, 8, 16);
      // T = P'V / rowsum + Fj: per-batch M=2048 N=512 K=1024
      gemm_bt<0,false,2><<<dim3(1024), blk, 0, stream>>>(
          Rg, nullptr, Vt + (long)b0 * PB_KV, nullptr,
          FjB + (long)b0 * PB_Q, Tout + (long)b0 * PB_Q,
          512, 1024, PB_S, PB_KV, PB_Q, 4, 16);
    }
    ln_k<<<dim3(16384), blk, 0, stream>>>(Tout, lng, lnb);
  }

  // --- fusion conv1d: Y = [T1|T2] @ Wf^T + bf (M=65536 N=512 K=1024) ---
  gemm_bt<1,true,0><<<dim3(2048), blk, 0, stream>>>(
      T1, T2, WfB, bfp, nullptr, Yb, 512, 1024, 0, 0, 0, 4, 512);

  // --- BatchNorm (train stats) + ReLU -> f32 out ---
  (void)hipMemsetAsync(stats, 0, 4096, stream);
  bn_stats_k<<<dim3(256), blk, 0, stream>>>(Yb, stats);
  bn_finalize_k<<<dim3(1), dim3(512), 0, stream>>>(stats, bng, bnb, ssbuf);
  bn_apply_k<<<dim3(16384), blk, 0, stream>>>(Yb, ssbuf, outp);
}